// Round 4
// baseline (592.673 us; speedup 1.0000x reference)
//
#include <hip/hip_runtime.h>
#include <math.h>

#define Dn 256
#define Hn 64

typedef __attribute__((ext_vector_type(8))) short short8;
typedef float floatx4 __attribute__((ext_vector_type(4)));

static __device__ __forceinline__ unsigned short f2bf(float x) {
    unsigned int u = __float_as_uint(x);
    unsigned int r = (u + 0x7fffu + ((u >> 16) & 1u)) >> 16;   // RNE
    return (unsigned short)r;
}

// async global->LDS, 16B/lane: lds dst = uniform base + lane*16
static __device__ __forceinline__ void dma16(const void* g, void* l) {
    __builtin_amdgcn_global_load_lds(
        (__attribute__((address_space(1))) void*)g,
        (__attribute__((address_space(3))) void*)l, 16, 0, 0);
}

// ---------------------------------------------------------------------------
// prep_wb: masked bf16 weights in MFMA B-fragment layout (sigmoid fused).
// Fragment (i, c, nb, lane, e) <-> kk = nb*16 + (lane&15), j = c*32 + (lane>>4)*8 + e
// Wb byte offset: i*32768 + (c*4+nb)*1024 + lane*16  (1KB per wave-fragment)
// grid (8, 256) = (c, i), block 256
// ---------------------------------------------------------------------------
__global__ __launch_bounds__(256) void prep_wb(const float* __restrict__ W1,
                                               const float* __restrict__ adj,
                                               unsigned short* __restrict__ Wb) {
    const int c = blockIdx.x, i = blockIdx.y;
    const int t = threadIdx.x;
    const int nb = t >> 6, l = t & 63;
    const int kk = nb * 16 + (l & 15);
    const int jb = c * 32 + ((l >> 4) & 3) * 8;
    const float* wp = W1 + ((size_t)i * Hn + kk) * Dn + jb;
    unsigned short v[8];
#pragma unroll
    for (int e = 0; e < 8; ++e) {
        int j = jb + e;
        float m = 0.f;
        if (j != i) m = 1.f / (1.f + __expf(-adj[(size_t)j * Dn + i]));
        v[e] = f2bf(wp[e] * m);
    }
    unsigned short* dst = Wb + ((((size_t)i * 8 + c) * 4 + nb) * 64 + l) * 8;
    *(short8*)dst = *(const short8*)v;
}

// ---------------------------------------------------------------------------
// prep_nst: nsT[d*B + b] = exp(log_sigma[d]) * noise[b*Dn + d]
// grid (B/64, Dn/64), block 256
// ---------------------------------------------------------------------------
__global__ __launch_bounds__(256) void prep_nst(const float* __restrict__ noise,
                                                const float* __restrict__ ls,
                                                float* __restrict__ nsT, int B) {
    __shared__ float tile[64][65];
    const int bi = blockIdx.x * 64, dj = blockIdx.y * 64;
    const int t = threadIdx.x, c = t & 63, rq = t >> 6;
#pragma unroll
    for (int it = 0; it < 16; ++it) {
        int b = bi + it * 4 + rq;
        tile[it * 4 + rq][c] = noise[(size_t)b * Dn + dj + c];
    }
    __syncthreads();
#pragma unroll
    for (int it = 0; it < 16; ++it) {
        int d = dj + it * 4 + rq;
        float sg = __expf(ls[d]);
        nsT[(size_t)d * B + bi + c] = tile[c][it * 4 + rq] * sg;
    }
}

// ---------------------------------------------------------------------------
// scm_main: sequential SCM. 2 waves/block; wave w owns 16 rows x all 64 hidden.
// B stream double-buffered in LDS via global_load_lds (no VGPR cost).
// z history lives in registers: af[7] frozen chunks + ain in-progress chunk
// (one bf16 element inserted per step). One __syncthreads per step; its
// implicit vmcnt drain is the DMA completion wait (DMA issued 1 step ahead).
// grid: B/32, block 128
// ---------------------------------------------------------------------------
__global__ __launch_bounds__(128, 1) void scm_main(const unsigned short* __restrict__ Wb,
                                                   const float* __restrict__ b1,
                                                   const float* __restrict__ W2,
                                                   const float* __restrict__ b2,
                                                   const float* __restrict__ nsT,
                                                   float* __restrict__ out, int B) {
    __shared__ unsigned char bbuf[2][32768];   // B double buffer (exactly 64KB)
    const int t = threadIdx.x;
    const int w = t >> 6, l = t & 63;
    const int n = l & 15, q = l >> 4;
    const int rowbase = blockIdx.x * 32 + w * 16;
    const unsigned char* wbb = (const unsigned char*)Wb;

    short8 af[7];                 // frozen 32-col chunks of this lane's A-row
    short8 ain = (short8)0;       // in-progress chunk
#pragma unroll
    for (int c = 0; c < 7; ++c) af[c] = (short8)0;

    float b1n[4], w2n[4], b2n;    // prefetched step params
    float4 nvn;
    float zout[4];

    // preload: DMA step 0 (chunk 0 only) + step-0 params
    for (int f = w; f < 4; f += 2)
        dma16(wbb + (size_t)f * 1024 + (size_t)l * 16, &bbuf[0][f * 1024]);
#pragma unroll
    for (int nb = 0; nb < 4; ++nb) {
        b1n[nb] = b1[nb * 16 + n];
        w2n[nb] = W2[nb * 16 + n];
    }
    nvn = *(const float4*)(nsT + rowbase + q * 4);
    b2n = b2[0];

#pragma unroll 1
    for (int sec = 0; sec < 8; ++sec) {
        // promote the chunk completed by the previous section
#pragma unroll
        for (int k2 = 0; k2 < 7; ++k2)
            if (sec == k2 + 1) af[k2] = ain;
        if (sec > 0) ain = (short8)0;

#pragma unroll 1
        for (int o = 0; o < 4; ++o) {
#pragma unroll
            for (int e8 = 0; e8 < 8; ++e8) {
                const int i = sec * 32 + o * 8 + e8;

                // drain own DMA(i) + barrier => whole buf[i&1] valid for both waves
                __syncthreads();

                // issue DMA(i+1) into the other buffer
                {
                    int ip = i + 1; if (ip > 255) ip = 255;
                    int nf = ((ip >> 5) + 1) * 4;
                    const unsigned char* src = wbb + (size_t)ip * 32768;
                    unsigned char* dstb = &bbuf[(i + 1) & 1][0];
                    for (int f = w; f < nf; f += 2)
                        dma16(src + (size_t)f * 1024 + (size_t)l * 16, dstb + f * 1024);
                }

                // current step params; prefetch next step's
                float b1c[4], w2c[4], nvr[4];
                float b2c = b2n;
#pragma unroll
                for (int nb = 0; nb < 4; ++nb) { b1c[nb] = b1n[nb]; w2c[nb] = w2n[nb]; }
                nvr[0] = nvn.x; nvr[1] = nvn.y; nvr[2] = nvn.z; nvr[3] = nvn.w;
                {
                    int ip = i + 1; if (ip > 255) ip = 255;
#pragma unroll
                    for (int nb = 0; nb < 4; ++nb) {
                        b1n[nb] = b1[ip * Hn + nb * 16 + n];
                        w2n[nb] = W2[ip * Hn + nb * 16 + n];
                    }
                    nvn = *(const float4*)(nsT + (size_t)ip * B + rowbase + q * 4);
                    b2n = b2[ip];
                }

                // MFMA over chunks 0..sec (cols >= i are zero in A -> harmless)
                const unsigned char* lbase = &bbuf[i & 1][0];
                floatx4 zero4 = {0.f, 0.f, 0.f, 0.f};
                floatx4 accA[4], accB[4];
#pragma unroll
                for (int nb = 0; nb < 4; ++nb) { accA[nb] = zero4; accB[nb] = zero4; }

#pragma unroll
                for (int c = 0; c < 7; ++c)
                    if (c < sec) {
#pragma unroll
                        for (int nb = 0; nb < 4; ++nb) {
                            short8 bfr = *(const short8*)(lbase + (size_t)(c * 4 + nb) * 1024 + (size_t)l * 16);
                            if (c & 1) accB[nb] = __builtin_amdgcn_mfma_f32_16x16x32_bf16(af[c], bfr, accB[nb], 0, 0, 0);
                            else       accA[nb] = __builtin_amdgcn_mfma_f32_16x16x32_bf16(af[c], bfr, accA[nb], 0, 0, 0);
                        }
                    }
#pragma unroll
                for (int nb = 0; nb < 4; ++nb) {
                    short8 bfr = *(const short8*)(lbase + (size_t)(sec * 4 + nb) * 1024 + (size_t)l * 16);
                    accB[nb] = __builtin_amdgcn_mfma_f32_16x16x32_bf16(ain, bfr, accB[nb], 0, 0, 0);
                }

                // epilogue: silu(h) . W2 over this wave's full 64 hidden
                float d[4];
#pragma unroll
                for (int r = 0; r < 4; ++r) {
                    float s = 0.f;
#pragma unroll
                    for (int nb = 0; nb < 4; ++nb) {
                        float h = accA[nb][r] + accB[nb][r] + b1c[nb];
                        s += __fdividef(h, 1.f + __expf(-h)) * w2c[nb];
                    }
                    d[r] = s;
                }
                // allreduce over the 16 n-lanes
#pragma unroll
                for (int m = 1; m <= 8; m <<= 1) {
#pragma unroll
                    for (int r = 0; r < 4; ++r) d[r] += __shfl_xor(d[r], m);
                }
                float z[4];
#pragma unroll
                for (int r = 0; r < 4; ++r) z[r] = d[r] + b2c + nvr[r];

                // zrow = z of row n (this lane's A-row)
                int srcl = ((l & 15) >> 2) << 4;
                float t0 = __shfl(z[0], srcl), t1 = __shfl(z[1], srcl);
                float t2 = __shfl(z[2], srcl), t3 = __shfl(z[3], srcl);
                float za = (l & 1) ? t1 : t0;
                float zb = (l & 1) ? t3 : t2;
                float zrow = (l & 2) ? zb : za;

                // insert bf16(zrow) into ain at k_loc = o*8 + e8 (owner quad o)
                unsigned short zb16 = f2bf(zrow);
                if (q == o) ain[e8] = (short)zb16;

                // batch output: one float4 store per 4 steps from q==0 lanes
                zout[e8 & 3] = zrow;
                if ((e8 & 3) == 3) {
                    if (q == 0) {
                        float4 v = make_float4(zout[0], zout[1], zout[2], zout[3]);
                        *(float4*)(out + (size_t)(rowbase + n) * Dn + (i - 3)) = v;
                    }
                }
            }
        }
    }
}

// ---------------------------------------------------------------------------
extern "C" void kernel_launch(void* const* d_in, const int* in_sizes, int n_in,
                              void* d_out, int out_size, void* d_ws, size_t ws_size,
                              hipStream_t stream) {
    const float* noise      = (const float*)d_in[0];
    const float* adj_logits = (const float*)d_in[1];
    const float* W1         = (const float*)d_in[2];
    const float* b1         = (const float*)d_in[3];
    const float* W2         = (const float*)d_in[4];
    const float* b2         = (const float*)d_in[5];
    const float* log_sigma  = (const float*)d_in[6];
    float* out = (float*)d_out;

    const int B = in_sizes[0] / Dn;                       // 8192
    unsigned short* Wb  = (unsigned short*)d_ws;          // 8.39 MB fragment weights
    float*          nsT = (float*)((char*)d_ws + (size_t)Dn * Dn * Hn * 2);

    prep_wb<<<dim3(8, Dn), 256, 0, stream>>>(W1, adj_logits, Wb);
    prep_nst<<<dim3(B / 64, Dn / 64), 256, 0, stream>>>(noise, log_sigma, nsT, B);
    scm_main<<<dim3(B / 32), 128, 0, stream>>>(Wb, b1, W2, b2, nsT, out, B);
}